// Round 1
// 1719.481 us; speedup vs baseline: 1.1498x; 1.1498x over previous
//
#include <hip/hip_runtime.h>
#include <hip/hip_bf16.h>

#define TCNT 8192   // B*S tokens
#define HDIM 1024
#define IDIM 2752
#define NEXP 8

#define BM 128
#define BN 64
#define BK 32

typedef short bf16x8 __attribute__((ext_vector_type(8)));
typedef float floatx4 __attribute__((ext_vector_type(4)));
typedef unsigned short ushortx8 __attribute__((ext_vector_type(8)));

__device__ __forceinline__ unsigned short f2bf(float f) {
    union { float f; unsigned u; } v; v.f = f;
    unsigned u = v.u;
    unsigned r = u + 0x7FFFu + ((u >> 16) & 1u);   // RNE
    return (unsigned short)(r >> 16);
}

// async global->LDS, 16B per lane; LDS dest = wave-uniform base + lane*16
__device__ __forceinline__ void async16(const unsigned short* g, unsigned short* l) {
    __builtin_amdgcn_global_load_lds(
        (const __attribute__((address_space(1))) unsigned int*)g,
        (__attribute__((address_space(3))) unsigned int*)l, 16, 0, 0);
}

// ---------------- cast x fp32 -> bf16 (once; reused by all 9 G/U passes) ----------------
__global__ void cast_x(const float* __restrict__ x, unsigned short* __restrict__ xb) {
    size_t i = (size_t)blockIdx.x * 256 + threadIdx.x;   // 8 elems per thread
    const float4* p = (const float4*)x + i * 2;
    float4 a = p[0], b = p[1];
    ushortx8 o;
    o[0] = f2bf(a.x); o[1] = f2bf(a.y); o[2] = f2bf(a.z); o[3] = f2bf(a.w);
    o[4] = f2bf(b.x); o[5] = f2bf(b.y); o[6] = f2bf(b.z); o[7] = f2bf(b.w);
    *(ushortx8*)(xb + i * 8) = o;
}

// ---------------- gate: softmax + top2, NO global atomics ----------------
__global__ void gate_kernel(const float* __restrict__ x,
                            const float* __restrict__ gw,
                            int* __restrict__ topi,
                            float* __restrict__ topw) {
    int wave = threadIdx.x >> 6;
    int lane = threadIdx.x & 63;
    int t = blockIdx.x * 4 + wave;
    float acc[NEXP];
#pragma unroll
    for (int e = 0; e < NEXP; e++) acc[e] = 0.f;
    const float* xp = x + (size_t)t * HDIM;
#pragma unroll
    for (int it = 0; it < HDIM / 64; it++) {
        float xv = xp[lane + 64 * it];
#pragma unroll
        for (int e = 0; e < NEXP; e++)
            acc[e] += xv * gw[e * HDIM + lane + 64 * it];
    }
#pragma unroll
    for (int e = 0; e < NEXP; e++) {
#pragma unroll
        for (int off = 32; off > 0; off >>= 1)
            acc[e] += __shfl_xor(acc[e], off);
    }
    if (lane == 0) {
        float m = acc[0];
#pragma unroll
        for (int e = 1; e < NEXP; e++) m = fmaxf(m, acc[e]);
        float p[NEXP], Z = 0.f;
#pragma unroll
        for (int e = 0; e < NEXP; e++) { p[e] = expf(acc[e] - m); Z += p[e]; }
        int i0 = 0;
#pragma unroll
        for (int e = 1; e < NEXP; e++) if (acc[e] > acc[i0]) i0 = e;
        int i1 = (i0 == 0) ? 1 : 0;
#pragma unroll
        for (int e = 0; e < NEXP; e++) {
            if (e == i0 || e == i1) continue;
            if (acc[e] > acc[i1]) i1 = e;
        }
        float p0 = p[i0] / Z, p1 = p[i1] / Z;
        float s = p0 + p1 + 1e-20f;
        topi[t * 2 + 0] = i0;  topw[t * 2 + 0] = p0 / s;
        topi[t * 2 + 1] = i1;  topw[t * 2 + 1] = p1 / s;
    }
}

// ---------------- compaction: one block per expert, LDS-atomic positions ----------------
__global__ void compact_k(const int* __restrict__ topi, const float* __restrict__ topw,
                          int* __restrict__ pcnt,
                          int* __restrict__ idxb, float* __restrict__ wgtb) {
    int e = blockIdx.x;
    __shared__ int base;
    if (threadIdx.x == 0) base = 0;
    __syncthreads();
    for (int i = threadIdx.x; i < 2 * TCNT; i += 256) {
        if (topi[i] == e) {
            int p = atomicAdd(&base, 1);       // LDS atomic — fast
            idxb[e * TCNT + p] = i >> 1;
            wgtb[e * TCNT + p] = topw[i];
        }
    }
    __syncthreads();
    int c = base;
    int pc = (c + BM - 1) & ~(BM - 1);
    for (int i = c + threadIdx.x; i < pc; i += 256) {
        idxb[e * TCNT + i] = 0;
        wgtb[e * TCNT + i] = 0.f;
    }
    if (threadIdx.x == 0) pcnt[e] = pc;
}

// ---------------- transpose + cast: in fp32 [R][C] -> out bf16 [C][R] ----------------
__global__ void trans2(const float* __restrict__ in0, const float* __restrict__ in1,
                       unsigned short* __restrict__ out0, unsigned short* __restrict__ out1,
                       int R, int C) {
    const float* in = blockIdx.z ? in1 : in0;
    unsigned short* out = blockIdx.z ? out1 : out0;
    __shared__ float tile[32][33];
    int r0 = blockIdx.y * 32, c0 = blockIdx.x * 32;
    int ty = threadIdx.x >> 3, tx = (threadIdx.x & 7) * 4;
    float4 v = *(const float4*)&in[(size_t)(r0 + ty) * C + c0 + tx];
    tile[ty][tx + 0] = v.x; tile[ty][tx + 1] = v.y;
    tile[ty][tx + 2] = v.z; tile[ty][tx + 3] = v.w;
    __syncthreads();
    int cy = ty, rx = tx;
    ushort4 o;
    o.x = f2bf(tile[rx + 0][cy]); o.y = f2bf(tile[rx + 1][cy]);
    o.z = f2bf(tile[rx + 2][cy]); o.w = f2bf(tile[rx + 3][cy]);
    *(ushort4*)&out[(size_t)(c0 + cy) * R + r0 + rx] = o;
}

// ---------------- fused G/U GEMM + SwiGLU (gathered rows) ----------------
// xb [T,H] bf16 (preferred) or x [T,H] fp32 fallback; GT,UT [I,H] bf16; Aout [cap,I] bf16
__global__ void gemm_gu(const float* __restrict__ x,
                        const unsigned short* __restrict__ xb,
                        const unsigned short* __restrict__ GT,
                        const unsigned short* __restrict__ UT,
                        const int* __restrict__ idx,    // per-expert list (+e*T) or null
                        const int* __restrict__ pcnt,   // padded count ptr or null
                        unsigned short* __restrict__ Aout) {
    const int m0 = blockIdx.x * BM;
    const int cnt = pcnt ? *pcnt : TCNT;
    if (m0 >= cnt) return;
    const int n0 = blockIdx.y * BN;

    __shared__ unsigned short Xs[BM][BK];   // unpadded (async-copy layout)
    __shared__ unsigned short Gs[BN][BK];
    __shared__ unsigned short Us[BN][BK];
    __shared__ int toks[BM];

    const int tid = threadIdx.x;
    const int wave = tid >> 6, lane = tid & 63;
    const int quad = lane >> 4, l16 = lane & 15;
    const int wm = wave >> 1, wn = wave & 1;   // wave tile: 64 m x 32 n

    if (tid < BM) toks[tid] = idx ? idx[m0 + tid] : (m0 + tid);
    __syncthreads();

    floatx4 aG[4][2], aU[4][2];
#pragma unroll
    for (int mi = 0; mi < 4; mi++)
#pragma unroll
        for (int nj = 0; nj < 2; nj++) {
            aG[mi][nj] = (floatx4){0.f, 0.f, 0.f, 0.f};
            aU[mi][nj] = (floatx4){0.f, 0.f, 0.f, 0.f};
        }

    const int rr = lane >> 2, cc = lane & 3;
    for (int kb = 0; kb < HDIM; kb += BK) {
        // weights: async 16B/lane, one wave stages 16 rows per matrix
        async16(GT + (size_t)(n0 + wave * 16 + rr) * HDIM + kb + cc * 8, &Gs[wave * 16][0]);
        async16(UT + (size_t)(n0 + wave * 16 + rr) * HDIM + kb + cc * 8, &Us[wave * 16][0]);
        if (xb) {
            // X: gathered rows straight from bf16 copy, async 16B/lane
#pragma unroll
            for (int s = 0; s < 2; s++) {
                int seg = wave * 2 + s;   // 0..7, 16 rows each
                async16(xb + (size_t)toks[seg * 16 + rr] * HDIM + kb + cc * 8,
                        &Xs[seg * 16][0]);
            }
        } else {
            // fallback: gather fp32 rows, convert in-register
#pragma unroll
            for (int r = 0; r < 4; r++) {
                int q = tid + r * 256;          // 0..1023
                int row = q >> 3, c = q & 7;
                const float* src = x + (size_t)toks[row] * HDIM + kb + c * 4;
                float4 v = *(const float4*)src;
                ushort4 o;
                o.x = f2bf(v.x); o.y = f2bf(v.y); o.z = f2bf(v.z); o.w = f2bf(v.w);
                *(ushort4*)&Xs[row][c * 4] = o;
            }
        }
        __syncthreads();

        bf16x8 af[4], bg[2], bu[2];
#pragma unroll
        for (int mi = 0; mi < 4; mi++)
            af[mi] = *(const bf16x8*)&Xs[wm * 64 + mi * 16 + l16][quad * 8];
#pragma unroll
        for (int nj = 0; nj < 2; nj++) {
            bg[nj] = *(const bf16x8*)&Gs[wn * 32 + nj * 16 + l16][quad * 8];
            bu[nj] = *(const bf16x8*)&Us[wn * 32 + nj * 16 + l16][quad * 8];
        }
#pragma unroll
        for (int mi = 0; mi < 4; mi++)
#pragma unroll
            for (int nj = 0; nj < 2; nj++) {
                aG[mi][nj] = __builtin_amdgcn_mfma_f32_16x16x32_bf16(af[mi], bg[nj], aG[mi][nj], 0, 0, 0);
                aU[mi][nj] = __builtin_amdgcn_mfma_f32_16x16x32_bf16(af[mi], bu[nj], aU[mi][nj], 0, 0, 0);
            }
        __syncthreads();
    }

#pragma unroll
    for (int mi = 0; mi < 4; mi++)
#pragma unroll
        for (int nj = 0; nj < 2; nj++)
#pragma unroll
            for (int r = 0; r < 4; r++) {
                int m = m0 + wm * 64 + mi * 16 + quad * 4 + r;
                int n = n0 + wn * 32 + nj * 16 + l16;
                float g = aG[mi][nj][r], u = aU[mi][nj][r];
                float a = g / (1.f + expf(-g)) * u;
                Aout[(size_t)m * IDIM + n] = f2bf(a);
            }
}

// ---------------- down GEMM: scatter-add w * (A @ WdT^T) into Y ----------------
// Ab [cap,I] bf16; WdT [H,I] bf16 (pre-transposed); Y [T,H] fp32
__global__ void gemm_down(const unsigned short* __restrict__ Ab,
                          const unsigned short* __restrict__ WdT,
                          const int* __restrict__ idx,
                          const float* __restrict__ wgt,
                          const int* __restrict__ pcnt,
                          float* __restrict__ Y) {
    const int m0 = blockIdx.x * BM;
    const int cnt = pcnt ? *pcnt : TCNT;
    if (m0 >= cnt) return;
    const int n0 = blockIdx.y * BN;

    __shared__ unsigned short As[BM][BK];
    __shared__ unsigned short Ws[BN][BK];
    __shared__ int toks[BM];
    __shared__ float tw[BM];

    const int tid = threadIdx.x;
    const int wave = tid >> 6, lane = tid & 63;
    const int quad = lane >> 4, l16 = lane & 15;
    const int wm = wave >> 1, wn = wave & 1;

    if (tid < BM) {
        toks[tid] = idx ? idx[m0 + tid] : (m0 + tid);
        tw[tid] = wgt ? wgt[m0 + tid] : 1.0f;
    }
    __syncthreads();

    floatx4 acc[4][2];
#pragma unroll
    for (int mi = 0; mi < 4; mi++)
#pragma unroll
        for (int nj = 0; nj < 2; nj++) acc[mi][nj] = (floatx4){0.f, 0.f, 0.f, 0.f};

    const int rr = lane >> 2, cc = lane & 3;
    for (int kb = 0; kb < IDIM; kb += BK) {
#pragma unroll
        for (int s = 0; s < 2; s++) {
            int seg = wave * 2 + s;   // 0..7, 16 rows each
            async16(Ab + (size_t)(m0 + seg * 16 + rr) * IDIM + kb + cc * 8, &As[seg * 16][0]);
        }
        async16(WdT + (size_t)(n0 + wave * 16 + rr) * IDIM + kb + cc * 8, &Ws[wave * 16][0]);
        __syncthreads();

        bf16x8 af[4], bw[2];
#pragma unroll
        for (int mi = 0; mi < 4; mi++)
            af[mi] = *(const bf16x8*)&As[wm * 64 + mi * 16 + l16][quad * 8];
#pragma unroll
        for (int nj = 0; nj < 2; nj++)
            bw[nj] = *(const bf16x8*)&Ws[wn * 32 + nj * 16 + l16][quad * 8];
#pragma unroll
        for (int mi = 0; mi < 4; mi++)
#pragma unroll
            for (int nj = 0; nj < 2; nj++)
                acc[mi][nj] = __builtin_amdgcn_mfma_f32_16x16x32_bf16(af[mi], bw[nj], acc[mi][nj], 0, 0, 0);
        __syncthreads();
    }

    if (idx) {  // routed: scatter atomic add (pad rows have weight 0)
#pragma unroll
        for (int mi = 0; mi < 4; mi++)
#pragma unroll
            for (int r = 0; r < 4; r++) {
                int lm = wm * 64 + mi * 16 + quad * 4 + r;
                int t = toks[lm];
                float w = tw[lm];
#pragma unroll
                for (int nj = 0; nj < 2; nj++) {
                    int n = n0 + wn * 32 + nj * 16 + l16;
                    atomicAdd(&Y[(size_t)t * HDIM + n], w * acc[mi][nj][r]);
                }
            }
    } else {    // shared expert: direct store (runs first, initializes Y)
#pragma unroll
        for (int mi = 0; mi < 4; mi++)
#pragma unroll
            for (int r = 0; r < 4; r++) {
                int m = m0 + wm * 64 + mi * 16 + quad * 4 + r;
#pragma unroll
                for (int nj = 0; nj < 2; nj++) {
                    int n = n0 + wn * 32 + nj * 16 + l16;
                    Y[(size_t)m * HDIM + n] = acc[mi][nj][r];
                }
            }
    }
}

extern "C" void kernel_launch(void* const* d_in, const int* in_sizes, int n_in,
                              void* d_out, int out_size, void* d_ws, size_t ws_size,
                              hipStream_t stream) {
    const float* x      = (const float*)d_in[0];
    const float* gate_w = (const float*)d_in[1];
    const float* wg     = (const float*)d_in[2];
    const float* wu     = (const float*)d_in[3];
    const float* wd     = (const float*)d_in[4];
    const float* sg     = (const float*)d_in[5];
    const float* su     = (const float*)d_in[6];
    const float* sd     = (const float*)d_in[7];
    float* y = (float*)d_out;

    const size_t HI = (size_t)HDIM * IDIM;
    unsigned short* WgT = (unsigned short*)d_ws;             // [I,H] bf16
    unsigned short* WuT = WgT + HI;                          // [I,H] bf16
    unsigned short* Ab  = WuT + HI;                          // [T,I] bf16
    int*   idxb = (int*)(Ab + (size_t)TCNT * IDIM);          // [E,T]
    float* wgtb = (float*)(idxb + NEXP * TCNT);              // [E,T]
    int*   pcnt = (int*)(wgtb + NEXP * TCNT);                // [E] (+pad to 16)
    int*   topi = pcnt + 16;                                 // [T,2]
    float* topw = (float*)(topi + 2 * TCNT);                 // [T,2]
    unsigned short* xb_cand = (unsigned short*)(topw + 2 * TCNT);  // [T,H] bf16
    size_t need = (size_t)((char*)xb_cand - (char*)d_ws) + (size_t)TCNT * HDIM * 2;
    unsigned short* xb = (ws_size >= need) ? xb_cand : nullptr;
    unsigned short* WdT = WgT;  // alias: WgT dead once gemm_gu(e) done; serialized on stream

    if (xb) cast_x<<<TCNT * HDIM / (256 * 8), 256, 0, stream>>>(x, xb);
    gate_kernel<<<TCNT / 4, 256, 0, stream>>>(x, gate_w, topi, topw);
    compact_k<<<NEXP, 256, 0, stream>>>(topi, topw, pcnt, idxb, wgtb);

    dim3 tg(IDIM / 32, HDIM / 32, 2);   // [H,I] -> [I,H], g+u
    dim3 td(HDIM / 32, IDIM / 32, 1);   // [I,H] -> [H,I]
    dim3 g1(TCNT / BM, IDIM / BN);      // 64 x 43
    dim3 g2(TCNT / BM, HDIM / BN);      // 64 x 16

    // shared expert first: down writes Y directly (no atomics)
    trans2<<<tg, 256, 0, stream>>>(sg, su, WgT, WuT, HDIM, IDIM);
    gemm_gu<<<g1, 256, 0, stream>>>(x, xb, WgT, WuT, nullptr, nullptr, Ab);
    trans2<<<td, 256, 0, stream>>>(sd, sd, WdT, WdT, IDIM, HDIM);
    gemm_down<<<g2, 256, 0, stream>>>(Ab, WdT, nullptr, nullptr, nullptr, y);

    // routed experts: compacted token lists, scatter-add
    for (int e = 0; e < NEXP; e++) {
        trans2<<<tg, 256, 0, stream>>>(wg + (size_t)e * HI, wu + (size_t)e * HI,
                                       WgT, WuT, HDIM, IDIM);
        gemm_gu<<<g1, 256, 0, stream>>>(x, xb, WgT, WuT, idxb + e * TCNT, pcnt + e, Ab);
        trans2<<<td, 256, 0, stream>>>(wd + (size_t)e * HI, wd, WdT, WdT, IDIM, HDIM);
        gemm_down<<<g2, 256, 0, stream>>>(Ab, WdT, idxb + e * TCNT, wgtb + e * TCNT,
                                          pcnt + e, y);
    }
}

// Round 2
// 1120.604 us; speedup vs baseline: 1.7642x; 1.5344x over previous
//
#include <hip/hip_runtime.h>
#include <hip/hip_bf16.h>

#define TCNT 8192   // B*S tokens
#define HDIM 1024
#define IDIM 2752
#define NEXP 8

#define BM 128
#define BN 64
// BK = 64 (128B LDS rows, XOR-swizzled)

#define ABCAP 25600  // 8192 shared + 16384 routed + 8*128 pad

typedef short bf16x8 __attribute__((ext_vector_type(8)));
typedef float floatx4 __attribute__((ext_vector_type(4)));
typedef unsigned short ushortx8 __attribute__((ext_vector_type(8)));

__device__ __forceinline__ unsigned short f2bf(float f) {
    union { float f; unsigned u; } v; v.f = f;
    unsigned u = v.u;
    unsigned r = u + 0x7FFFu + ((u >> 16) & 1u);   // RNE
    return (unsigned short)(r >> 16);
}

// async global->LDS, 16B per lane; LDS dest = wave-uniform base + lane*16
__device__ __forceinline__ void async16(const unsigned short* g, unsigned short* l) {
    __builtin_amdgcn_global_load_lds(
        (const __attribute__((address_space(1))) unsigned int*)g,
        (__attribute__((address_space(3))) unsigned int*)l, 16, 0, 0);
}

// ---------------- cast x fp32 -> bf16 (once; reused by all 9 G/U passes) ----------------
__global__ void cast_x(const float* __restrict__ x, unsigned short* __restrict__ xb) {
    size_t i = (size_t)blockIdx.x * 256 + threadIdx.x;   // 8 elems per thread
    const float4* p = (const float4*)x + i * 2;
    float4 a = p[0], b = p[1];
    ushortx8 o;
    o[0] = f2bf(a.x); o[1] = f2bf(a.y); o[2] = f2bf(a.z); o[3] = f2bf(a.w);
    o[4] = f2bf(b.x); o[5] = f2bf(b.y); o[6] = f2bf(b.z); o[7] = f2bf(b.w);
    *(ushortx8*)(xb + i * 8) = o;
}

// ---------------- gate: softmax + top2, no global atomics ----------------
__global__ void gate_kernel(const float* __restrict__ x,
                            const float* __restrict__ gw,
                            int* __restrict__ topi,
                            float* __restrict__ topw) {
    int wave = threadIdx.x >> 6;
    int lane = threadIdx.x & 63;
    int t = blockIdx.x * 4 + wave;
    float acc[NEXP];
#pragma unroll
    for (int e = 0; e < NEXP; e++) acc[e] = 0.f;
    const float* xp = x + (size_t)t * HDIM;
#pragma unroll
    for (int it = 0; it < HDIM / 64; it++) {
        float xv = xp[lane + 64 * it];
#pragma unroll
        for (int e = 0; e < NEXP; e++)
            acc[e] += xv * gw[e * HDIM + lane + 64 * it];
    }
#pragma unroll
    for (int e = 0; e < NEXP; e++) {
#pragma unroll
        for (int off = 32; off > 0; off >>= 1)
            acc[e] += __shfl_xor(acc[e], off);
    }
    if (lane == 0) {
        float m = acc[0];
#pragma unroll
        for (int e = 1; e < NEXP; e++) m = fmaxf(m, acc[e]);
        float p[NEXP], Z = 0.f;
#pragma unroll
        for (int e = 0; e < NEXP; e++) { p[e] = expf(acc[e] - m); Z += p[e]; }
        int i0 = 0;
#pragma unroll
        for (int e = 1; e < NEXP; e++) if (acc[e] > acc[i0]) i0 = e;
        int i1 = (i0 == 0) ? 1 : 0;
#pragma unroll
        for (int e = 0; e < NEXP; e++) {
            if (e == i0 || e == i1) continue;
            if (acc[e] > acc[i1]) i1 = e;
        }
        float p0 = p[i0] / Z, p1 = p[i1] / Z;
        float s = p0 + p1 + 1e-20f;
        topi[t * 2 + 0] = i0;  topw[t * 2 + 0] = p0 / s;
        topi[t * 2 + 1] = i1;  topw[t * 2 + 1] = p1 / s;
    }
}

// ---------------- compaction: one block per expert, LDS-atomic positions ----------------
__global__ void compact_k(const int* __restrict__ topi, const float* __restrict__ topw,
                          int* __restrict__ pcnt,
                          int* __restrict__ idxb, float* __restrict__ wgtb) {
    int e = blockIdx.x;
    __shared__ int base;
    if (threadIdx.x == 0) base = 0;
    __syncthreads();
    for (int i = threadIdx.x; i < 2 * TCNT; i += 256) {
        if (topi[i] == e) {
            int p = atomicAdd(&base, 1);       // LDS atomic — fast
            idxb[e * TCNT + p] = i >> 1;
            wgtb[e * TCNT + p] = topw[i];
        }
    }
    __syncthreads();
    int c = base;
    int pc = (c + BM - 1) & ~(BM - 1);
    for (int i = c + threadIdx.x; i < pc; i += 256) {
        idxb[e * TCNT + i] = 0;
        wgtb[e * TCNT + i] = 0.f;
    }
    if (threadIdx.x == 0) pcnt[e] = pc;
}

// ---------------- Ab row offsets: shared at 0, routed slices after ----------------
__global__ void offsets_k(const int* __restrict__ pcnt, int* __restrict__ abrow, int fused) {
    if (threadIdx.x == 0) {
        int off = TCNT;   // routed region starts after shared slice
        for (int e = 0; e < NEXP; e++) {
            abrow[e] = fused ? off : 0;
            off += pcnt[e];
        }
        abrow[8] = 0;     // shared slice base
    }
}

// ---------------- transpose+cast G/U: [H,I] fp32 -> [I,H] bf16 ----------------
// z -> (expert e = z>>1, which = z&1 : 0=g 1=u); e==8 means shared (sg/su)
__global__ void trans_gu_all(const float* __restrict__ wg, const float* __restrict__ sg,
                             const float* __restrict__ wu, const float* __restrict__ su,
                             unsigned short* __restrict__ outg, unsigned short* __restrict__ outu,
                             int zbase, size_t ostride) {
    const size_t HI = (size_t)HDIM * IDIM;
    int z = zbase + blockIdx.z;
    int e = z >> 1, which = z & 1;
    const float* in = which ? (e < 8 ? wu + (size_t)e * HI : su)
                            : (e < 8 ? wg + (size_t)e * HI : sg);
    unsigned short* out = (which ? outu : outg) + (size_t)e * ostride;
    const int R = HDIM, C = IDIM;
    __shared__ float tile[32][33];
    int r0 = blockIdx.y * 32, c0 = blockIdx.x * 32;
    int ty = threadIdx.x >> 3, tx = (threadIdx.x & 7) * 4;
    float4 v = *(const float4*)&in[(size_t)(r0 + ty) * C + c0 + tx];
    tile[ty][tx + 0] = v.x; tile[ty][tx + 1] = v.y;
    tile[ty][tx + 2] = v.z; tile[ty][tx + 3] = v.w;
    __syncthreads();
    int cy = ty, rx = tx;
    ushort4 o;
    o.x = f2bf(tile[rx + 0][cy]); o.y = f2bf(tile[rx + 1][cy]);
    o.z = f2bf(tile[rx + 2][cy]); o.w = f2bf(tile[rx + 3][cy]);
    *(ushort4*)&out[(size_t)(c0 + cy) * R + r0 + rx] = o;
}

// ---------------- transpose+cast D: [I,H] fp32 -> [H,I] bf16 ----------------
__global__ void trans_d_all(const float* __restrict__ wd, const float* __restrict__ sd,
                            unsigned short* __restrict__ outd, int zbase, size_t ostride) {
    const size_t HI = (size_t)HDIM * IDIM;
    int e = zbase + blockIdx.z;
    const float* in = (e < 8) ? wd + (size_t)e * HI : sd;
    unsigned short* out = outd + (size_t)e * ostride;
    const int R = IDIM, C = HDIM;
    __shared__ float tile[32][33];
    int r0 = blockIdx.y * 32, c0 = blockIdx.x * 32;
    int ty = threadIdx.x >> 3, tx = (threadIdx.x & 7) * 4;
    float4 v = *(const float4*)&in[(size_t)(r0 + ty) * C + c0 + tx];
    tile[ty][tx + 0] = v.x; tile[ty][tx + 1] = v.y;
    tile[ty][tx + 2] = v.z; tile[ty][tx + 3] = v.w;
    __syncthreads();
    int cy = ty, rx = tx;
    ushort4 o;
    o.x = f2bf(tile[rx + 0][cy]); o.y = f2bf(tile[rx + 1][cy]);
    o.z = f2bf(tile[rx + 2][cy]); o.w = f2bf(tile[rx + 3][cy]);
    *(ushort4*)&out[(size_t)(c0 + cy) * R + r0 + rx] = o;
}

// ---------------- fused G/U GEMM + SwiGLU, all experts (z = expert; 8 = shared) ----
// BK=64, XOR-swizzled LDS (inverse swizzle on global src, swizzle on ds_read)
__global__ void gemm_gu_all(const float* __restrict__ x,
                            const unsigned short* __restrict__ xb,
                            const unsigned short* __restrict__ Wg,
                            const unsigned short* __restrict__ Wu,
                            size_t wstride,
                            const int* __restrict__ idxb,
                            const int* __restrict__ pcnt,
                            const int* __restrict__ abrow,
                            unsigned short* __restrict__ Ab,
                            int zbase) {
    const int e = zbase + blockIdx.z;
    const int cnt = (e == 8) ? TCNT : pcnt[e];
    const int m0 = blockIdx.x * BM;
    if (m0 >= cnt) return;
    const int n0 = blockIdx.y * BN;
    const unsigned short* GT = Wg + (size_t)e * wstride;
    const unsigned short* UT = Wu + (size_t)e * wstride;
    const int* idx = (e == 8) ? nullptr : idxb + e * TCNT;
    const int ab0 = abrow[e];

    __shared__ unsigned short Xs[BM][64];
    __shared__ unsigned short Gs[BN][64];
    __shared__ unsigned short Us[BN][64];
    __shared__ int toks[BM];

    const int tid = threadIdx.x;
    const int wave = tid >> 6, lane = tid & 63;
    const int quad = lane >> 4, l16 = lane & 15;
    const int wm = wave >> 1, wn = wave & 1;   // wave tile: 64 m x 32 n

    if (tid < BM) toks[tid] = idx ? idx[m0 + tid] : (m0 + tid);
    __syncthreads();

    floatx4 aG[4][2], aU[4][2];
#pragma unroll
    for (int mi = 0; mi < 4; mi++)
#pragma unroll
        for (int nj = 0; nj < 2; nj++) {
            aG[mi][nj] = (floatx4){0.f, 0.f, 0.f, 0.f};
            aU[mi][nj] = (floatx4){0.f, 0.f, 0.f, 0.f};
        }

    const int rr = lane >> 3, cc = lane & 7;
    const int sw = (cc ^ rr) * 8;              // inverse-swizzled global slot (8 elems)
    for (int kb = 0; kb < HDIM; kb += 64) {
        async16(GT + (size_t)(n0 + wave * 16 + rr) * HDIM + kb + sw, &Gs[wave * 16][0]);
        async16(GT + (size_t)(n0 + wave * 16 + 8 + rr) * HDIM + kb + sw, &Gs[wave * 16 + 8][0]);
        async16(UT + (size_t)(n0 + wave * 16 + rr) * HDIM + kb + sw, &Us[wave * 16][0]);
        async16(UT + (size_t)(n0 + wave * 16 + 8 + rr) * HDIM + kb + sw, &Us[wave * 16 + 8][0]);
        if (xb) {
#pragma unroll
            for (int s = 0; s < 4; s++) {
                int b = wave * 32 + s * 8;
                async16(xb + (size_t)toks[b + rr] * HDIM + kb + sw, &Xs[b][0]);
            }
        } else {
            // fallback: gather fp32 rows, convert in-register, swizzled ds_write
#pragma unroll
            for (int r = 0; r < 4; r++) {
                int q = tid + r * 256;          // 0..1023 16B-chunks
                int row = q >> 3, g = q & 7;
                const float* src = x + (size_t)toks[row] * HDIM + kb + g * 8;
                float4 v0 = *(const float4*)src, v1 = *(const float4*)(src + 4);
                ushortx8 o;
                o[0] = f2bf(v0.x); o[1] = f2bf(v0.y); o[2] = f2bf(v0.z); o[3] = f2bf(v0.w);
                o[4] = f2bf(v1.x); o[5] = f2bf(v1.y); o[6] = f2bf(v1.z); o[7] = f2bf(v1.w);
                *(ushortx8*)&Xs[row][(g ^ (row & 7)) * 8] = o;
            }
        }
        __syncthreads();

#pragma unroll
        for (int h = 0; h < 2; h++) {
            bf16x8 af[4], bg[2], bu[2];
#pragma unroll
            for (int mi = 0; mi < 4; mi++) {
                int row = wm * 64 + mi * 16 + l16;
                af[mi] = *(const bf16x8*)&Xs[row][(((h << 2) + quad) ^ (row & 7)) * 8];
            }
#pragma unroll
            for (int nj = 0; nj < 2; nj++) {
                int row = wn * 32 + nj * 16 + l16;
                int so = (((h << 2) + quad) ^ (row & 7)) * 8;
                bg[nj] = *(const bf16x8*)&Gs[row][so];
                bu[nj] = *(const bf16x8*)&Us[row][so];
            }
#pragma unroll
            for (int mi = 0; mi < 4; mi++)
#pragma unroll
                for (int nj = 0; nj < 2; nj++) {
                    aG[mi][nj] = __builtin_amdgcn_mfma_f32_16x16x32_bf16(af[mi], bg[nj], aG[mi][nj], 0, 0, 0);
                    aU[mi][nj] = __builtin_amdgcn_mfma_f32_16x16x32_bf16(af[mi], bu[nj], aU[mi][nj], 0, 0, 0);
                }
        }
        __syncthreads();
    }

#pragma unroll
    for (int mi = 0; mi < 4; mi++)
#pragma unroll
        for (int nj = 0; nj < 2; nj++)
#pragma unroll
            for (int r = 0; r < 4; r++) {
                int m = ab0 + m0 + wm * 64 + mi * 16 + quad * 4 + r;
                int n = n0 + wn * 32 + nj * 16 + l16;
                float g = aG[mi][nj][r], u = aU[mi][nj][r];
                float a = g / (1.f + expf(-g)) * u;
                Ab[(size_t)m * IDIM + n] = f2bf(a);
            }
}

// ---------------- down GEMM, all experts; shared (e==8) stores, routed scatter-adds --
__global__ void gemm_down_all(const unsigned short* __restrict__ Ab,
                              const unsigned short* __restrict__ Wd,
                              size_t wstride,
                              const int* __restrict__ idxb,
                              const float* __restrict__ wgtb,
                              const int* __restrict__ pcnt,
                              const int* __restrict__ abrow,
                              float* __restrict__ Y,
                              int zbase) {
    const int e = zbase + blockIdx.z;
    const int cnt = (e == 8) ? TCNT : pcnt[e];
    const int m0 = blockIdx.x * BM;
    if (m0 >= cnt) return;
    const int n0 = blockIdx.y * BN;
    const unsigned short* DT = Wd + (size_t)e * wstride;
    const int* idx = (e == 8) ? nullptr : idxb + e * TCNT;
    const float* wgt = (e == 8) ? nullptr : wgtb + e * TCNT;
    const int ab0 = abrow[e];

    __shared__ unsigned short As[BM][64];
    __shared__ unsigned short Ws[BN][64];
    __shared__ int toks[BM];
    __shared__ float tw[BM];

    const int tid = threadIdx.x;
    const int wave = tid >> 6, lane = tid & 63;
    const int quad = lane >> 4, l16 = lane & 15;
    const int wm = wave >> 1, wn = wave & 1;

    if (tid < BM) {
        toks[tid] = idx ? idx[m0 + tid] : (m0 + tid);
        tw[tid] = wgt ? wgt[m0 + tid] : 1.0f;
    }
    __syncthreads();

    floatx4 acc[4][2];
#pragma unroll
    for (int mi = 0; mi < 4; mi++)
#pragma unroll
        for (int nj = 0; nj < 2; nj++) acc[mi][nj] = (floatx4){0.f, 0.f, 0.f, 0.f};

    const int rr = lane >> 3, cc = lane & 7;
    const int sw = (cc ^ rr) * 8;
    for (int kb = 0; kb < IDIM; kb += 64) {
#pragma unroll
        for (int s = 0; s < 4; s++) {
            int b = wave * 32 + s * 8;
            async16(Ab + (size_t)(ab0 + m0 + b + rr) * IDIM + kb + sw, &As[b][0]);
        }
        async16(DT + (size_t)(n0 + wave * 16 + rr) * IDIM + kb + sw, &Ws[wave * 16][0]);
        async16(DT + (size_t)(n0 + wave * 16 + 8 + rr) * IDIM + kb + sw, &Ws[wave * 16 + 8][0]);
        __syncthreads();

#pragma unroll
        for (int h = 0; h < 2; h++) {
            bf16x8 af[4], bw[2];
#pragma unroll
            for (int mi = 0; mi < 4; mi++) {
                int row = wm * 64 + mi * 16 + l16;
                af[mi] = *(const bf16x8*)&As[row][(((h << 2) + quad) ^ (row & 7)) * 8];
            }
#pragma unroll
            for (int nj = 0; nj < 2; nj++) {
                int row = wn * 32 + nj * 16 + l16;
                bw[nj] = *(const bf16x8*)&Ws[row][(((h << 2) + quad) ^ (row & 7)) * 8];
            }
#pragma unroll
            for (int mi = 0; mi < 4; mi++)
#pragma unroll
                for (int nj = 0; nj < 2; nj++)
                    acc[mi][nj] = __builtin_amdgcn_mfma_f32_16x16x32_bf16(af[mi], bw[nj], acc[mi][nj], 0, 0, 0);
        }
        __syncthreads();
    }

    if (e != 8) {  // routed: scatter atomic add (pad rows have weight 0)
#pragma unroll
        for (int mi = 0; mi < 4; mi++)
#pragma unroll
            for (int r = 0; r < 4; r++) {
                int lm = wm * 64 + mi * 16 + quad * 4 + r;
                int t = toks[lm];
                float w = tw[lm];
#pragma unroll
                for (int nj = 0; nj < 2; nj++) {
                    int n = n0 + wn * 32 + nj * 16 + l16;
                    atomicAdd(&Y[(size_t)t * HDIM + n], w * acc[mi][nj][r]);
                }
            }
    } else {       // shared expert: direct store (runs first, initializes Y)
#pragma unroll
        for (int mi = 0; mi < 4; mi++)
#pragma unroll
            for (int r = 0; r < 4; r++) {
                int m = m0 + wm * 64 + mi * 16 + quad * 4 + r;
#pragma unroll
                for (int nj = 0; nj < 2; nj++) {
                    int n = n0 + wn * 32 + nj * 16 + l16;
                    Y[(size_t)m * HDIM + n] = acc[mi][nj][r];
                }
            }
    }
}

extern "C" void kernel_launch(void* const* d_in, const int* in_sizes, int n_in,
                              void* d_out, int out_size, void* d_ws, size_t ws_size,
                              hipStream_t stream) {
    const float* x      = (const float*)d_in[0];
    const float* gate_w = (const float*)d_in[1];
    const float* wg     = (const float*)d_in[2];
    const float* wu     = (const float*)d_in[3];
    const float* wd     = (const float*)d_in[4];
    const float* sg     = (const float*)d_in[5];
    const float* su     = (const float*)d_in[6];
    const float* sd     = (const float*)d_in[7];
    float* y = (float*)d_out;

    const size_t HI   = (size_t)HDIM * IDIM;
    const size_t XB_B = (size_t)TCNT * HDIM * 2;          // 16.78 MB
    const size_t LISTS_B = (size_t)NEXP * TCNT * 8 + (size_t)4 * TCNT * 4 + 256;
    const size_t full_need = XB_B + 18 * HI * 2 + (size_t)ABCAP * IDIM * 2 + LISTS_B; // ~260 MB

    if (ws_size >= full_need) {
        // -------- fused mode: 9 launches total --------
        unsigned short* xb  = (unsigned short*)d_ws;
        unsigned short* WgA = xb + (size_t)TCNT * HDIM;   // [9][I][H]
        unsigned short* WuA = WgA + 9 * HI;               // [9][I][H]
        unsigned short* WdA = WgA;                        // alias: trans_d runs after gu_all
        unsigned short* Ab  = WuA + 9 * HI;               // [ABCAP][I]
        int*   idxb  = (int*)(Ab + (size_t)ABCAP * IDIM);
        float* wgtb  = (float*)(idxb + NEXP * TCNT);
        int*   topi  = (int*)(wgtb + NEXP * TCNT);
        float* topw  = (float*)(topi + 2 * TCNT);
        int*   pcnt  = (int*)(topw + 2 * TCNT);
        int*   abrow = pcnt + 16;

        cast_x<<<TCNT * HDIM / (256 * 8), 256, 0, stream>>>(x, xb);
        gate_kernel<<<TCNT / 4, 256, 0, stream>>>(x, gate_w, topi, topw);
        compact_k<<<NEXP, 256, 0, stream>>>(topi, topw, pcnt, idxb, wgtb);
        offsets_k<<<1, 64, 0, stream>>>(pcnt, abrow, 1);

        trans_gu_all<<<dim3(IDIM / 32, HDIM / 32, 18), 256, 0, stream>>>(
            wg, sg, wu, su, WgA, WuA, 0, HI);
        gemm_gu_all<<<dim3(TCNT / BM, IDIM / BN, 9), 256, 0, stream>>>(
            x, xb, WgA, WuA, HI, idxb, pcnt, abrow, Ab, 0);
        trans_d_all<<<dim3(HDIM / 32, IDIM / 32, 9), 256, 0, stream>>>(wd, sd, WdA, 0, HI);
        // shared first (direct store initializes Y), then routed scatter-add
        gemm_down_all<<<dim3(TCNT / BM, HDIM / BN, 1), 256, 0, stream>>>(
            Ab, WdA, HI, idxb, wgtb, pcnt, abrow, y, 8);
        gemm_down_all<<<dim3(TCNT / BM, HDIM / BN, 8), 256, 0, stream>>>(
            Ab, WdA, HI, idxb, wgtb, pcnt, abrow, y, 0);
    } else {
        // -------- fallback: sequential per-expert (round-1 footprint) --------
        unsigned short* WgT = (unsigned short*)d_ws;      // [I][H]
        unsigned short* WuT = WgT + HI;
        unsigned short* Ab  = WuT + HI;                   // [T][I]
        int*   idxb  = (int*)(Ab + (size_t)TCNT * IDIM);
        float* wgtb  = (float*)(idxb + NEXP * TCNT);
        int*   topi  = (int*)(wgtb + NEXP * TCNT);
        float* topw  = (float*)(topi + 2 * TCNT);
        int*   pcnt  = (int*)(topw + 2 * TCNT);
        int*   abrow = pcnt + 16;
        unsigned short* xbc = (unsigned short*)(abrow + 16);
        size_t small_need = (size_t)((char*)xbc - (char*)d_ws) + XB_B;
        unsigned short* xb = (ws_size >= small_need) ? xbc : nullptr;
        unsigned short* WdT = WgT;  // alias; serialized on stream

        if (xb) cast_x<<<TCNT * HDIM / (256 * 8), 256, 0, stream>>>(x, xb);
        gate_kernel<<<TCNT / 4, 256, 0, stream>>>(x, gate_w, topi, topw);
        compact_k<<<NEXP, 256, 0, stream>>>(topi, topw, pcnt, idxb, wgtb);
        offsets_k<<<1, 64, 0, stream>>>(pcnt, abrow, 0);

        // shared expert
        trans_gu_all<<<dim3(IDIM / 32, HDIM / 32, 2), 256, 0, stream>>>(
            wg, sg, wu, su, WgT, WuT, 16, 0);
        gemm_gu_all<<<dim3(TCNT / BM, IDIM / BN, 1), 256, 0, stream>>>(
            x, xb, WgT, WuT, 0, idxb, pcnt, abrow, Ab, 8);
        trans_d_all<<<dim3(HDIM / 32, IDIM / 32, 1), 256, 0, stream>>>(wd, sd, WdT, 8, 0);
        gemm_down_all<<<dim3(TCNT / BM, HDIM / BN, 1), 256, 0, stream>>>(
            Ab, WdT, 0, idxb, wgtb, pcnt, abrow, y, 8);

        for (int e = 0; e < NEXP; e++) {
            trans_gu_all<<<dim3(IDIM / 32, HDIM / 32, 2), 256, 0, stream>>>(
                wg, sg, wu, su, WgT, WuT, 2 * e, 0);
            gemm_gu_all<<<dim3(TCNT / BM, IDIM / BN, 1), 256, 0, stream>>>(
                x, xb, WgT, WuT, 0, idxb, pcnt, abrow, Ab, e);
            trans_d_all<<<dim3(HDIM / 32, IDIM / 32, 1), 256, 0, stream>>>(wd, sd, WdT, e, 0);
            gemm_down_all<<<dim3(TCNT / BM, HDIM / BN, 1), 256, 0, stream>>>(
                Ab, WdT, 0, idxb, wgtb, pcnt, abrow, y, e);
        }
    }
}